// Round 3
// baseline (801.984 us; speedup 1.0000x reference)
//
#include <hip/hip_runtime.h>
#include <math.h>

// Problem constants
#define NB 16      // batch
#define NE 128     // experts / channels
#define NK 8
#define HW 16384   // 128*128
#define NPIX (NB * HW)

typedef float v2f __attribute__((ext_vector_type(2)));

// f32 transposed gate weights: gwT[e][f] = gate_w[f][e]
__device__ float g_gwT[NE * NE];

__global__ __launch_bounds__(256) void cvt_gw_kernel(const float* __restrict__ gate_w) {
    int i = blockIdx.x * 256 + threadIdx.x;   // i = e*128 + f
    if (i < NE * NE) {
        int e = i >> 7;
        int f = i & 127;
        g_gwT[i] = gate_w[f * NE + e];
    }
}

// One e-step: acc[j] (f=2j,2j+1) += gw[e][2j,2j+1] * x[e]  via packed f32 FMA.
// Each half of v_pk_fma_f32 is an exact IEEE f32 FMA -> bit-identical to the
// scalar fmaf chain (same per-f accumulation order over ascending e).
#define E_STEP(EIDX, XV)                                                \
    {                                                                   \
        v2f xb; xb.x = (XV); xb.y = (XV);                               \
        const v2f* g2 = (const v2f*)&g_gwT[(size_t)(EIDX) * NE];        \
        _Pragma("unroll")                                               \
        for (int j = 0; j < NE / 2; ++j) {                              \
            asm("v_pk_fma_f32 %0, %2, %1, %0"                           \
                : "+v"(acc[j])                                          \
                : "v"(xb), "s"(g2[j]));                                 \
        }                                                               \
    }

__global__ __launch_bounds__(256, 2) void moe_kernel(const float* __restrict__ experts,
                                                     const float* __restrict__ gate_b,
                                                     float* __restrict__ out) {
    const int p  = blockIdx.x * 256 + threadIdx.x;   // pixel id
    const int n  = p >> 14;                          // /16384
    const int hw = p & (HW - 1);

    const float* xp = experts + ((size_t)n * NE * HW + hw);   // channel stride HW

    v2f acc[NE / 2];
#pragma unroll
    for (int j = 0; j < NE / 2; ++j) acc[j] = (v2f){0.0f, 0.0f};

    // ---- logits: software-pipelined, packed-FMA matvec ----
    float xc0 = xp[0 * (size_t)HW];
    float xc1 = xp[1 * (size_t)HW];
    float xc2 = xp[2 * (size_t)HW];
    float xc3 = xp[3 * (size_t)HW];

    int e = 0;
    for (; e < NE - 4; e += 4) {   // e = 0..120; each iter prefetches e+4..e+7
        float nx0 = xp[(size_t)(e + 4) * HW];
        float nx1 = xp[(size_t)(e + 5) * HW];
        float nx2 = xp[(size_t)(e + 6) * HW];
        float nx3 = xp[(size_t)(e + 7) * HW];
        E_STEP(e + 0, xc0);
        E_STEP(e + 1, xc1);
        E_STEP(e + 2, xc2);
        E_STEP(e + 3, xc3);
        xc0 = nx0; xc1 = nx1; xc2 = nx2; xc3 = nx3;
    }
    // tail: e = 124..127, already prefetched
    E_STEP(e + 0, xc0);
    E_STEP(e + 1, xc1);
    E_STEP(e + 2, xc2);
    E_STEP(e + 3, xc3);

    // ---- + bias (after the chain, exactly as the passing version) ----
#pragma unroll
    for (int j = 0; j < NE / 2; ++j) {
        acc[j].x = acc[j].x + gate_b[2 * j];
        acc[j].y = acc[j].y + gate_b[2 * j + 1];
    }

    // ---- softmax, f32 numpy semantics (bit-frozen from the passing version) ----
    float m = acc[0].x;
    m = fmaxf(m, acc[0].y);
#pragma unroll
    for (int j = 1; j < NE / 2; ++j) {
        m = fmaxf(m, acc[j].x);
        m = fmaxf(m, acc[j].y);
    }

    // correctly-rounded f32 exp of (l - m)
#pragma unroll
    for (int j = 0; j < NE / 2; ++j) {
        acc[j].x = (float)exp((double)(acc[j].x - m));
        acc[j].y = (float)exp((double)(acc[j].y - m));
    }

    // denominator: sequential ascending-f f32 sum
    float s = acc[0].x;
    s = s + acc[0].y;
#pragma unroll
    for (int j = 1; j < NE / 2; ++j) {
        s = s + acc[j].x;
        s = s + acc[j].y;
    }

    // routing weights: IEEE f32 divide (rank space -> must mirror)
#pragma unroll
    for (int j = 0; j < NE / 2; ++j) {
        acc[j].x = acc[j].x / s;
        acc[j].y = acc[j].y / s;
    }

    // ---- top-8 on (w desc, idx asc): ascending-f insertion, strict '>' ----
    float t_v[NK];
    int   t_i[NK];
#pragma unroll
    for (int i = 0; i < NK; ++i) { t_v[i] = -1.0f; t_i[i] = 0; }

#pragma unroll
    for (int j = 0; j < NE / 2; ++j) {
#pragma unroll
        for (int h = 0; h < 2; ++h) {
            float v  = h ? acc[j].y : acc[j].x;
            int   ix = 2 * j + h;
#pragma unroll
            for (int i = 0; i < NK; ++i) {
                bool gt = v > t_v[i];
                float tv = t_v[i]; int ti = t_i[i];
                t_v[i] = gt ? v  : tv;
                t_i[i] = gt ? ix : ti;
                v      = gt ? tv : v;
                ix     = gt ? ti : ix;
            }
        }
    }

    // ---- gather + scale + write ----
    float* op = out + ((size_t)n * NK * HW + hw);
#pragma unroll
    for (int k = 0; k < NK; ++k) {
        float xv = xp[(size_t)t_i[k] * HW];
        op[(size_t)k * HW] = t_v[k] * xv;
    }
}

extern "C" void kernel_launch(void* const* d_in, const int* in_sizes, int n_in,
                              void* d_out, int out_size, void* d_ws, size_t ws_size,
                              hipStream_t stream) {
    // inputs: 0=x (unused), 1=experts [N,E,H,W] f32, 2=gate_w [E,E] f32, 3=gate_b [E] f32
    const float* experts = (const float*)d_in[1];
    const float* gate_w  = (const float*)d_in[2];
    const float* gate_b  = (const float*)d_in[3];
    float* out = (float*)d_out;

    hipLaunchKernelGGL(cvt_gw_kernel, dim3((NE * NE + 255) / 256), dim3(256), 0, stream, gate_w);
    hipLaunchKernelGGL(moe_kernel, dim3(NPIX / 256), dim3(256), 0, stream, experts, gate_b, out);
}